// Round 1
// baseline (361.688 us; speedup 1.0000x reference)
//
#include <hip/hip_runtime.h>
#include <cstdint>
#include <cstddef>

// GIN: B=32, N=1024, FIN=128, H1=64, H2=32, OUT=10. adj binary, ~1% dense.
// Pipeline:
//   k_proj1 : u = x @ W1a                       [32768 x 64]
//   k_layerA: ballot-scan adj rows (134 MB, the HBM-bound pass), emit CSR,
//             pre = u_i + sum_j u_j + b1a; h2 = relu(pre)@W2a + b2a;
//             v = (h2*mask)@W1b                 [32768 x 32]
//   k_layerB: aggregate v via CSR; h3 = (relu(v_i+sum v_j+b1b)@W2b+b2b)*mask
//   k_readout: g = max_n h3; out = g@Wfc + bfc
// adj read exactly ONCE (layer B uses the CSR built in layer A).

#define NB 32768          // B*N
#define CAP 64            // max degree kept in CSR (P(deg>64) ~ e-66/node)

typedef float v4f __attribute__((ext_vector_type(4)));

// ---------------- u = x @ W1a  (32768x128 @ 128x64) ----------------
// One wave computes 8 rows; x row values are wave-uniform (broadcast loads),
// W1a column element per lane from LDS (one ds_read_b32 feeds 8 FMAs).
__global__ __launch_bounds__(256) void k_proj1(
    const float* __restrict__ x, const float* __restrict__ W1a,
    float* __restrict__ u) {
  __shared__ float sW[128 * 64];   // 32 KB
  for (int t = threadIdx.x; t < 128 * 64; t += 256) sW[t] = W1a[t];
  __syncthreads();
  int lane = threadIdx.x & 63;
  int wid  = threadIdx.x >> 6;
  int row0 = (blockIdx.x * 4 + wid) * 8;           // grid 1024 -> 32768 rows
  row0 = __builtin_amdgcn_readfirstlane(row0);     // force wave-uniform (SGPR)
  const float* xr = x + (size_t)row0 * 128;
  float acc[8] = {0, 0, 0, 0, 0, 0, 0, 0};
  for (int kc = 0; kc < 32; ++kc) {
    v4f xv[8];
    #pragma unroll
    for (int r = 0; r < 8; ++r)
      xv[r] = *(const v4f*)(xr + r * 128 + kc * 4);  // uniform-address loads
    #pragma unroll
    for (int j = 0; j < 4; ++j) {
      float w = sW[(kc * 4 + j) * 64 + lane];
      #pragma unroll
      for (int r = 0; r < 8; ++r)
        acc[r] = fmaf(xv[r][j], w, acc[r]);
    }
  }
  #pragma unroll
  for (int r = 0; r < 8; ++r)
    u[(size_t)(row0 + r) * 64 + lane] = acc[r];
}

// ---------------- layer A: aggregate + MLP + project to v ----------------
// One wave per node. adj row read as 4x float4/lane (1 KB per instruction,
// nontemporal: streamed once). __ballot finds nonzeros; each set bit is a
// wave-uniform scalar j -> coalesced 256 B gather of u[j]. W2a column and
// W1b half-column live in VGPRs (no LDS traffic in the MLP).
__global__ __launch_bounds__(256) void k_layerA(
    const float* __restrict__ adj, const float* __restrict__ u,
    const float* __restrict__ mask,
    const float* __restrict__ b1a, const float* __restrict__ W2a,
    const float* __restrict__ b2a, const float* __restrict__ W1b,
    float* __restrict__ v, int* __restrict__ nbr, int* __restrict__ deg) {
  int lane = threadIdx.x & 63;
  int f = lane & 31, hh = lane >> 5;
  float w2[64];                       // W2a column `lane`
  #pragma unroll
  for (int k = 0; k < 64; ++k) w2[k] = W2a[k * 64 + lane];
  float w1b[32];                      // W1b rows hh*32..hh*32+31, column f
  #pragma unroll
  for (int k0 = 0; k0 < 32; ++k0) w1b[k0] = W1b[(hh * 32 + k0) * 32 + f];
  float ba1 = b1a[lane], ba2 = b2a[lane];
  int gw = blockIdx.x * 4 + (threadIdx.x >> 6);    // grid 2048 -> 8192 waves
  #pragma unroll 1
  for (int it = 0; it < 4; ++it) {
    int node = gw * 4 + it;                        // 4 consecutive nodes/wave
    const v4f* arow = (const v4f*)(adj + (size_t)node * 1024);
    const float* ub = u + (size_t)(node & ~1023) * 64;   // batch base
    float acc = ub[(node & 1023) * 64 + lane];           // self term (eps=0)
    int cnt = 0;
    #pragma unroll
    for (int c = 0; c < 4; ++c) {
      v4f a4 = __builtin_nontemporal_load(arow + c * 64 + lane);
      #pragma unroll
      for (int comp = 0; comp < 4; ++comp) {
        unsigned long long m = __ballot(a4[comp] != 0.0f);
        while (m) {
          int s = (int)__builtin_ctzll(m);
          m &= m - 1;
          int j = ((c * 64 + s) << 2) + comp;      // wave-uniform scalar
          acc += ub[j * 64 + lane];                // coalesced 256 B gather
          if (lane == 0 && cnt < CAP) nbr[node * CAP + cnt] = j;
          ++cnt;
        }
      }
    }
    if (lane == 0) deg[node] = cnt < CAP ? cnt : CAP;
    float r = fmaxf(acc + ba1, 0.0f);
    float h2 = ba2;
    #pragma unroll
    for (int k = 0; k < 64; ++k)                   // r_k via v_readlane
      h2 = fmaf(__shfl(r, k), w2[k], h2);
    h2 *= mask[node];
    // v = h2 @ W1b : halves split the k-range, then cross-half add
    float vp = 0.0f;
    #pragma unroll
    for (int k0 = 0; k0 < 32; ++k0)
      vp = fmaf(__shfl(h2, hh * 32 + k0), w1b[k0], vp);
    vp += __shfl_xor(vp, 32);
    if (hh == 0) v[node * 32 + f] = vp;
  }
}

// ---------------- layer B: aggregate v via CSR + MLP -> h3 ----------------
// One wave per node, two neighbors per iteration (half-wave each). Neighbor
// indices prefetched into one register/lane, broadcast with __shfl so the
// gather loads pipeline (no load->load dependency chain).
__global__ __launch_bounds__(256) void k_layerB(
    const float* __restrict__ v, const int* __restrict__ nbr,
    const int* __restrict__ deg, const float* __restrict__ mask,
    const float* __restrict__ b1b, const float* __restrict__ W2b,
    const float* __restrict__ b2b, float* __restrict__ h3) {
  int lane = threadIdx.x & 63;
  int f = lane & 31, hh = lane >> 5;
  float w2b[32];
  #pragma unroll
  for (int k = 0; k < 32; ++k) w2b[k] = W2b[k * 32 + f];
  float bb1 = b1b[f], bb2 = b2b[f];
  int gw = blockIdx.x * 4 + (threadIdx.x >> 6);    // grid 4096 -> 16384 waves
  #pragma unroll 1
  for (int it = 0; it < 2; ++it) {
    int node = gw * 2 + it;
    const float* vb = v + (size_t)(node & ~1023) * 32;
    int d = deg[node];
    int nli = nbr[node * CAP + lane];              // prefetch whole list
    float acc = 0.0f;
    for (int t = hh; t < d; t += 2) {
      int j = __shfl(nli, t);                      // bpermute broadcast
      acc += vb[j * 32 + f];                       // 128 B gather per half
    }
    acc += __shfl_xor(acc, 32);                    // combine halves
    float pre = vb[(node & 1023) * 32 + f] + acc + bb1;
    float r = fmaxf(pre, 0.0f);
    float o = bb2;
    #pragma unroll
    for (int k = 0; k < 32; ++k)
      o = fmaf(__shfl(r, k), w2b[k], o);
    o *= mask[node];
    if (hh == 0) h3[node * 32 + f] = o;
  }
}

// ---------------- readout: g = max_n h3 ; out = g@Wfc + bfc ----------------
__global__ __launch_bounds__(1024) void k_readout(
    const float* __restrict__ h3, const float* __restrict__ Wfc,
    const float* __restrict__ bfc, float* __restrict__ out) {
  __shared__ float red[32][33];
  __shared__ float g[32];
  int b = blockIdx.x;
  int f = threadIdx.x & 31, c = threadIdx.x >> 5;  // 32 chunks of 32 rows
  const float* hb = h3 + (size_t)b * 1024 * 32;
  float m = -3.4e38f;
  for (int r0 = 0; r0 < 32; ++r0)
    m = fmaxf(m, hb[(c * 32 + r0) * 32 + f]);
  red[c][f] = m;
  __syncthreads();
  if (c == 0) {
    float mm = red[0][f];
    #pragma unroll
    for (int k = 1; k < 32; ++k) mm = fmaxf(mm, red[k][f]);
    g[f] = mm;
  }
  __syncthreads();
  if (threadIdx.x < 10) {
    float o = bfc[threadIdx.x];
    #pragma unroll
    for (int k = 0; k < 32; ++k)
      o = fmaf(g[k], Wfc[k * 10 + threadIdx.x], o);
    out[b * 10 + threadIdx.x] = o;
  }
}

extern "C" void kernel_launch(void* const* d_in, const int* in_sizes, int n_in,
                              void* d_out, int out_size, void* d_ws, size_t ws_size,
                              hipStream_t stream) {
  const float* x    = (const float*)d_in[0];
  const float* adj  = (const float*)d_in[1];
  const float* mask = (const float*)d_in[2];
  const float* W1a  = (const float*)d_in[3];
  const float* b1a  = (const float*)d_in[4];
  const float* W2a  = (const float*)d_in[5];
  const float* b2a  = (const float*)d_in[6];
  const float* W1b  = (const float*)d_in[7];
  const float* b1b  = (const float*)d_in[8];
  const float* W2b  = (const float*)d_in[9];
  const float* b2b  = (const float*)d_in[10];
  const float* Wfc  = (const float*)d_in[11];
  const float* bfc  = (const float*)d_in[12];
  float* out = (float*)d_out;

  // Workspace layout (h3 reuses u's space; u is dead after k_layerA):
  //   u   : [0, 8 MB)       NB*64 f32
  //   v   : [8 MB, 12 MB)   NB*32 f32
  //   nbr : [12 MB, 20 MB)  NB*CAP i32
  //   deg : [20 MB, +128 K) NB i32
  //   h3  : [0, 4 MB)       NB*32 f32 (aliases dead u)
  char* ws = (char*)d_ws;
  float* u   = (float*)(ws);
  float* v   = (float*)(ws + (8u << 20));
  int*   nbr = (int*)  (ws + (12u << 20));
  int*   deg = (int*)  (ws + (20u << 20));
  float* h3  = (float*)(ws);

  hipLaunchKernelGGL(k_proj1,   dim3(1024), dim3(256),  0, stream, x, W1a, u);
  hipLaunchKernelGGL(k_layerA,  dim3(2048), dim3(256),  0, stream,
                     adj, u, mask, b1a, W2a, b2a, W1b, v, nbr, deg);
  hipLaunchKernelGGL(k_layerB,  dim3(4096), dim3(256),  0, stream,
                     v, nbr, deg, mask, b1b, W2b, b2b, h3);
  hipLaunchKernelGGL(k_readout, dim3(32),   dim3(1024), 0, stream,
                     h3, Wfc, bfc, out);
}

// Round 2
// 321.701 us; speedup vs baseline: 1.1243x; 1.1243x over previous
//
#include <hip/hip_runtime.h>
#include <cstdint>
#include <cstddef>

// GIN: B=32, N=1024, FIN=128, H1=64, H2=32, OUT=10. adj binary, ~1% dense.
// Round-2 structure: decouple the HBM stream from latency chains.
//   k_proj1 : u = x @ W1a                        [32768 x 64] f32
//   k_scan  : stream adj (134 MB) ONCE -> CSR (nbr/deg), lane-parallel
//             mbcnt extraction, no gathers, no MLP -> full BW
//   k_gathA : neigh-sum from CSR (8 loads in flight) + MLP -> v [32768 x 32]
//   k_gathB : neigh-sum of v from CSR + MLP -> h3 [32768 x 32]
//   k_readout: g = max_n h3; out = g@Wfc + bfc
// All f32 exact (no bf16 rounding anywhere).

#define CAP 64            // max degree kept (Binomial(1024,.01): max ~30)

typedef float v4f __attribute__((ext_vector_type(4)));

__device__ __forceinline__ float rl(float x, int l) {   // wave-uniform lane bcast
  return __int_as_float(__builtin_amdgcn_readlane(__float_as_int(x), l));
}

// ---------------- u = x @ W1a  (32768x128 @ 128x64) ----------------
__global__ __launch_bounds__(256) void k_proj1(
    const float* __restrict__ x, const float* __restrict__ W1a,
    float* __restrict__ u) {
  __shared__ float sW[128 * 64];   // 32 KB
  for (int t = threadIdx.x; t < 128 * 64; t += 256) sW[t] = W1a[t];
  __syncthreads();
  int lane = threadIdx.x & 63;
  int wid  = threadIdx.x >> 6;
  int row0 = (blockIdx.x * 4 + wid) * 8;           // grid 1024 -> 32768 rows
  row0 = __builtin_amdgcn_readfirstlane(row0);
  const float* xr = x + (size_t)row0 * 128;
  float acc[8] = {0, 0, 0, 0, 0, 0, 0, 0};
  for (int kc = 0; kc < 32; ++kc) {
    v4f xv[8];
    #pragma unroll
    for (int r = 0; r < 8; ++r)
      xv[r] = *(const v4f*)(xr + r * 128 + kc * 4);
    #pragma unroll
    for (int j = 0; j < 4; ++j) {
      float w = sW[(kc * 4 + j) * 64 + lane];
      #pragma unroll
      for (int r = 0; r < 8; ++r)
        acc[r] = fmaf(xv[r][j], w, acc[r]);
    }
  }
  #pragma unroll
  for (int r = 0; r < 8; ++r)
    u[(size_t)(row0 + r) * 64 + lane] = acc[r];
}

// ---------------- scan adj -> CSR (the one HBM-bound pass) ----------------
// One wave per node row (4 KB). Ballot finds nonzeros; every set lane writes
// its own column index at slot cnt + mbcnt-prefix. No serial while loop, no
// dependent loads -> the 4 row loads stay in flight, stream at HBM rate.
__global__ __launch_bounds__(256) void k_scan(
    const float* __restrict__ adj, int* __restrict__ nbr,
    int* __restrict__ deg) {
  int lane = threadIdx.x & 63;
  int node = blockIdx.x * 4 + (threadIdx.x >> 6);  // grid 8192 -> 32768 rows
  const v4f* arow = (const v4f*)(adj + (size_t)node * 1024);
  int* out = nbr + node * CAP;
  v4f a[4];
  #pragma unroll
  for (int c = 0; c < 4; ++c)
    a[c] = __builtin_nontemporal_load(arow + c * 64 + lane);  // 4 KB row
  int cnt = 0;
  #pragma unroll
  for (int c = 0; c < 4; ++c) {
    #pragma unroll
    for (int comp = 0; comp < 4; ++comp) {
      bool hit = (a[c][comp] != 0.0f);
      unsigned long long m = __ballot(hit);
      if (hit) {
        int below = __builtin_amdgcn_mbcnt_hi(
            (unsigned)(m >> 32),
            __builtin_amdgcn_mbcnt_lo((unsigned)m, 0));
        int pos = cnt + below;
        if (pos < CAP) out[pos] = ((c * 64 + lane) << 2) + comp;
      }
      cnt += __popcll(m);
    }
  }
  if (lane == 0) deg[node] = cnt < CAP ? cnt : CAP;
}

// ---------------- layer A: gather from CSR + MLP -> v ----------------
// One wave per node (4 nodes sequentially). Gather loop: fixed-trip masked
// rounds of 8 with 8 independent accumulators -> 8 loads in flight, one
// vmcnt wait per round instead of per neighbor.
__global__ __launch_bounds__(256) void k_gathA(
    const float* __restrict__ u, const int* __restrict__ nbr,
    const int* __restrict__ deg, const float* __restrict__ mask,
    const float* __restrict__ b1a, const float* __restrict__ W2a,
    const float* __restrict__ b2a, const float* __restrict__ W1b,
    float* __restrict__ v) {
  int lane = threadIdx.x & 63;
  int f = lane & 31, hh = lane >> 5;
  float w2[64];                       // W2a column `lane` in VGPRs
  #pragma unroll
  for (int k = 0; k < 64; ++k) w2[k] = W2a[k * 64 + lane];
  float w1b[32];                      // W1b rows hh*32.., column f
  #pragma unroll
  for (int k0 = 0; k0 < 32; ++k0) w1b[k0] = W1b[(hh * 32 + k0) * 32 + f];
  float ba1 = b1a[lane], ba2 = b2a[lane];
  int gw = blockIdx.x * 4 + (threadIdx.x >> 6);    // grid 2048 -> 8192 waves
  #pragma unroll 1
  for (int it = 0; it < 4; ++it) {
    int node = gw * 4 + it;
    const float* ub = u + (size_t)(node & ~1023) * 64;
    int d = deg[node];
    int nli = nbr[node * CAP + lane];              // whole list, 1 reg/lane
    float s[8] = {0, 0, 0, 0, 0, 0, 0, 0};
    int rounds = (d + 7) >> 3;
    for (int rr = 0; rr < rounds; ++rr) {
      int base = rr << 3;
      #pragma unroll
      for (int i = 0; i < 8; ++i) {
        int t = base + i;                          // uniform, <= 63
        int j = __builtin_amdgcn_readlane(nli, t);
        bool ok = t < d;
        j = ok ? j : 0;                            // clamp poison index
        float val = ub[j * 64 + lane];             // 8 independent 256B gathers
        s[i] += ok ? val : 0.0f;
      }
    }
    float acc = ub[(node & 1023) * 64 + lane]      // self term (eps=0)
              + (((s[0] + s[1]) + (s[2] + s[3])) + ((s[4] + s[5]) + (s[6] + s[7])));
    float r = fmaxf(acc + ba1, 0.0f);
    // h2 = r @ W2a + b2a : 4 parallel fma chains, readlane broadcasts
    float h0 = 0, h1 = 0, h2c = 0, h3c = 0;
    #pragma unroll
    for (int k = 0; k < 64; k += 4) {
      h0  = fmaf(rl(r, k    ), w2[k    ], h0);
      h1  = fmaf(rl(r, k + 1), w2[k + 1], h1);
      h2c = fmaf(rl(r, k + 2), w2[k + 2], h2c);
      h3c = fmaf(rl(r, k + 3), w2[k + 3], h3c);
    }
    float h2 = (ba2 + ((h0 + h1) + (h2c + h3c))) * mask[node];
    // v = h2 @ W1b : halves split k-range, 2 chains each, cross-half add
    float vp0 = 0, vp1 = 0;
    #pragma unroll
    for (int k0 = 0; k0 < 32; k0 += 2) {
      vp0 = fmaf(__shfl(h2, hh * 32 + k0    ), w1b[k0    ], vp0);
      vp1 = fmaf(__shfl(h2, hh * 32 + k0 + 1), w1b[k0 + 1], vp1);
    }
    float vp = vp0 + vp1;
    vp += __shfl_xor(vp, 32);
    if (hh == 0) v[node * 32 + f] = vp;
  }
}

// ---------------- layer B: gather v from CSR + MLP -> h3 ----------------
// One wave per node; halves handle alternating neighbors (128 B rows), 8
// accumulators -> up to 8 loads in flight per half.
__global__ __launch_bounds__(256) void k_gathB(
    const float* __restrict__ v, const int* __restrict__ nbr,
    const int* __restrict__ deg, const float* __restrict__ mask,
    const float* __restrict__ b1b, const float* __restrict__ W2b,
    const float* __restrict__ b2b, float* __restrict__ h3) {
  int lane = threadIdx.x & 63;
  int f = lane & 31, hh = lane >> 5;
  float w2b[32];
  #pragma unroll
  for (int k = 0; k < 32; ++k) w2b[k] = W2b[k * 32 + f];
  float bb1 = b1b[f], bb2 = b2b[f];
  int gw = blockIdx.x * 4 + (threadIdx.x >> 6);    // grid 2048 -> 8192 waves
  #pragma unroll 1
  for (int it = 0; it < 4; ++it) {
    int node = gw * 4 + it;
    const float* vb = v + (size_t)(node & ~1023) * 32;
    int d = deg[node];
    int nli = nbr[node * CAP + lane];
    float s[8] = {0, 0, 0, 0, 0, 0, 0, 0};
    int rounds = (d + 15) >> 4;                    // 16 neighbors per round
    for (int rr = 0; rr < rounds; ++rr) {
      int base = rr << 4;
      #pragma unroll
      for (int i = 0; i < 8; ++i) {
        int t = base + (i << 1) + hh;              // divergent by half
        int j = __shfl(nli, t);
        bool ok = t < d;
        j = ok ? j : 0;
        float val = vb[j * 32 + f];                // 128 B per half-wave
        s[i] += ok ? val : 0.0f;
      }
    }
    float acc = ((s[0] + s[1]) + (s[2] + s[3])) + ((s[4] + s[5]) + (s[6] + s[7]));
    acc += __shfl_xor(acc, 32);                    // combine halves
    float pre = vb[(node & 1023) * 32 + f] + acc + bb1;
    float r = fmaxf(pre, 0.0f);
    float o0 = 0, o1 = 0, o2 = 0, o3 = 0;
    #pragma unroll
    for (int k = 0; k < 32; k += 4) {
      o0 = fmaf(rl(r, k    ), w2b[k    ], o0);
      o1 = fmaf(rl(r, k + 1), w2b[k + 1], o1);
      o2 = fmaf(rl(r, k + 2), w2b[k + 2], o2);
      o3 = fmaf(rl(r, k + 3), w2b[k + 3], o3);
    }
    float o = (bb2 + ((o0 + o1) + (o2 + o3))) * mask[node];
    if (hh == 0) h3[node * 32 + f] = o;
  }
}

// ---------------- readout: g = max_n h3 ; out = g@Wfc + bfc ----------------
__global__ __launch_bounds__(1024) void k_readout(
    const float* __restrict__ h3, const float* __restrict__ Wfc,
    const float* __restrict__ bfc, float* __restrict__ out) {
  __shared__ float red[32][33];
  __shared__ float g[32];
  int b = blockIdx.x;
  int f = threadIdx.x & 31, c = threadIdx.x >> 5;
  const float* hb = h3 + (size_t)b * 1024 * 32;
  float m = -3.4e38f;
  for (int r0 = 0; r0 < 32; ++r0)
    m = fmaxf(m, hb[(c * 32 + r0) * 32 + f]);
  red[c][f] = m;
  __syncthreads();
  if (c == 0) {
    float mm = red[0][f];
    #pragma unroll
    for (int k = 1; k < 32; ++k) mm = fmaxf(mm, red[k][f]);
    g[f] = mm;
  }
  __syncthreads();
  if (threadIdx.x < 10) {
    float o = bfc[threadIdx.x];
    #pragma unroll
    for (int k = 0; k < 32; ++k)
      o = fmaf(g[k], Wfc[k * 10 + threadIdx.x], o);
    out[b * 10 + threadIdx.x] = o;
  }
}

extern "C" void kernel_launch(void* const* d_in, const int* in_sizes, int n_in,
                              void* d_out, int out_size, void* d_ws, size_t ws_size,
                              hipStream_t stream) {
  const float* x    = (const float*)d_in[0];
  const float* adj  = (const float*)d_in[1];
  const float* mask = (const float*)d_in[2];
  const float* W1a  = (const float*)d_in[3];
  const float* b1a  = (const float*)d_in[4];
  const float* W2a  = (const float*)d_in[5];
  const float* b2a  = (const float*)d_in[6];
  const float* W1b  = (const float*)d_in[7];
  const float* b1b  = (const float*)d_in[8];
  const float* W2b  = (const float*)d_in[9];
  const float* b2b  = (const float*)d_in[10];
  const float* Wfc  = (const float*)d_in[11];
  const float* bfc  = (const float*)d_in[12];
  float* out = (float*)d_out;

  // ws layout: u[0,8M) v[8M,12M) nbr[12M,20M) deg[20M,+128K) h3 aliases u
  char* ws = (char*)d_ws;
  float* u   = (float*)(ws);
  float* v   = (float*)(ws + (8u << 20));
  int*   nbr = (int*)  (ws + (12u << 20));
  int*   deg = (int*)  (ws + (20u << 20));
  float* h3  = (float*)(ws);

  hipLaunchKernelGGL(k_scan,    dim3(8192), dim3(256),  0, stream, adj, nbr, deg);
  hipLaunchKernelGGL(k_proj1,   dim3(1024), dim3(256),  0, stream, x, W1a, u);
  hipLaunchKernelGGL(k_gathA,   dim3(2048), dim3(256),  0, stream,
                     u, nbr, deg, mask, b1a, W2a, b2a, W1b, v);
  hipLaunchKernelGGL(k_gathB,   dim3(2048), dim3(256),  0, stream,
                     v, nbr, deg, mask, b1b, W2b, b2b, h3);
  hipLaunchKernelGGL(k_readout, dim3(32),   dim3(1024), 0, stream,
                     h3, Wfc, bfc, out);
}

// Round 3
// 297.791 us; speedup vs baseline: 1.2146x; 1.0803x over previous
//
#include <hip/hip_runtime.h>
#include <cstdint>
#include <cstddef>

// GIN: B=32, N=1024, FIN=128, H1=64, H2=32, OUT=10. adj binary, ~1% dense.
// Round-3: LDS-resident weights (round-1 VGPR=84 proved register arrays were
// NOT kept resident -> per-FMA global reloads), 2-node-batched MLP chains
// (one weight ds_read feeds 2 fmas), scan+proj fused with block
// specialization so the projection GEMM hides under the adj HBM stream.
//   k_scanproj: blocks 0..1023 -> u = x@W1a ; blocks 1024..9215 -> adj scan->CSR
//   k_gathA   : neigh-sum u via CSR (16 loads in flight) + MLP -> v
//   k_gathB   : neigh-sum v via CSR + MLP -> h3
//   k_readout : g = max_n h3; out = g@Wfc + bfc

#define CAP 64

typedef float v4f __attribute__((ext_vector_type(4)));

__device__ __forceinline__ float rl(float x, int l) {   // wave-uniform lane bcast
  return __int_as_float(__builtin_amdgcn_readlane(__float_as_int(x), l));
}

// ---------------- fused: proj (u = x@W1a) + scan (adj -> CSR) ----------------
__global__ __launch_bounds__(256) void k_scanproj(
    const float* __restrict__ x, const float* __restrict__ W1a,
    float* __restrict__ u,
    const float* __restrict__ adj, int* __restrict__ nbr,
    int* __restrict__ deg) {
  __shared__ float sW[128 * 64];   // 32 KB (proj blocks only)
  int lane = threadIdx.x & 63;
  int wid  = threadIdx.x >> 6;
  if (blockIdx.x < 1024) {
    // ---- proj: u = x @ W1a, 8 rows/wave ----
    for (int t = threadIdx.x; t < 128 * 64; t += 256) sW[t] = W1a[t];
    __syncthreads();
    int row0 = (blockIdx.x * 4 + wid) * 8;
    row0 = __builtin_amdgcn_readfirstlane(row0);
    const float* xr = x + (size_t)row0 * 128;
    float acc[8] = {0, 0, 0, 0, 0, 0, 0, 0};
    for (int kc = 0; kc < 32; ++kc) {
      v4f xv[8];
      #pragma unroll
      for (int r = 0; r < 8; ++r)
        xv[r] = *(const v4f*)(xr + r * 128 + kc * 4);
      #pragma unroll
      for (int j = 0; j < 4; ++j) {
        float w = sW[(kc * 4 + j) * 64 + lane];
        #pragma unroll
        for (int r = 0; r < 8; ++r)
          acc[r] = fmaf(xv[r][j], w, acc[r]);
      }
    }
    #pragma unroll
    for (int r = 0; r < 8; ++r)
      u[(size_t)(row0 + r) * 64 + lane] = acc[r];
  } else {
    // ---- scan: one wave per 4 KB adj row, lane-parallel index extraction ----
    int node = (blockIdx.x - 1024) * 4 + wid;      // 8192 blocks -> 32768 rows
    const v4f* arow = (const v4f*)(adj + (size_t)node * 1024);
    int* outp = nbr + node * CAP;
    v4f a[4];
    #pragma unroll
    for (int c = 0; c < 4; ++c)
      a[c] = __builtin_nontemporal_load(arow + c * 64 + lane);
    int cnt = 0;
    #pragma unroll
    for (int c = 0; c < 4; ++c) {
      #pragma unroll
      for (int comp = 0; comp < 4; ++comp) {
        bool hit = (a[c][comp] != 0.0f);
        unsigned long long m = __ballot(hit);
        if (hit) {
          int below = __builtin_amdgcn_mbcnt_hi(
              (unsigned)(m >> 32),
              __builtin_amdgcn_mbcnt_lo((unsigned)m, 0));
          int pos = cnt + below;
          if (pos < CAP) outp[pos] = ((c * 64 + lane) << 2) + comp;
        }
        cnt += __popcll(m);
      }
    }
    if (lane == 0) deg[node] = cnt < CAP ? cnt : CAP;
  }
}

// ---------------- layer A: gather u via CSR + MLP -> v ----------------
// One wave per 2 nodes; gathers for both nodes issued jointly (16 loads in
// flight), MLP batched so each LDS weight read feeds two fmas.
__global__ __launch_bounds__(256) void k_gathA(
    const float* __restrict__ u, const int* __restrict__ nbr,
    const int* __restrict__ deg, const float* __restrict__ mask,
    const float* __restrict__ b1a, const float* __restrict__ W2a,
    const float* __restrict__ b2a, const float* __restrict__ W1b,
    float* __restrict__ v) {
  __shared__ float sW2[64 * 64];    // 16 KB
  __shared__ float sW1b[64 * 32];   // 8 KB
  for (int t = threadIdx.x; t < 64 * 64; t += 256) sW2[t] = W2a[t];
  for (int t = threadIdx.x; t < 64 * 32; t += 256) sW1b[t] = W1b[t];
  __syncthreads();
  int lane = threadIdx.x & 63;
  int f = lane & 31, hh = lane >> 5;
  float ba1 = b1a[lane], ba2 = b2a[lane];
  int gw = blockIdx.x * 4 + (threadIdx.x >> 6);    // grid 4096 -> 16384 waves
  int n0 = gw * 2, n1 = n0 + 1;                    // same batch (1024 even)
  const float* ub = u + (size_t)(n0 & ~1023) * 64;
  int d0 = deg[n0], d1 = deg[n1];
  int nl0 = nbr[n0 * CAP + lane], nl1 = nbr[n1 * CAP + lane];
  float s0[8] = {0,0,0,0,0,0,0,0}, s1[8] = {0,0,0,0,0,0,0,0};
  int dmax = d0 > d1 ? d0 : d1;
  int rounds = (dmax + 7) >> 3;
  for (int rr = 0; rr < rounds; ++rr) {
    int base = rr << 3;
    #pragma unroll
    for (int i = 0; i < 8; ++i) {
      int t = base + i;
      int j0 = __builtin_amdgcn_readlane(nl0, t);
      int j1 = __builtin_amdgcn_readlane(nl1, t);
      bool ok0 = t < d0, ok1 = t < d1;
      j0 = ok0 ? j0 : 0;  j1 = ok1 ? j1 : 0;
      float v0 = ub[j0 * 64 + lane];               // 16 independent gathers
      float v1 = ub[j1 * 64 + lane];
      s0[i] += ok0 ? v0 : 0.0f;
      s1[i] += ok1 ? v1 : 0.0f;
    }
  }
  float acc0 = ub[(n0 & 1023) * 64 + lane]
             + (((s0[0]+s0[1])+(s0[2]+s0[3]))+((s0[4]+s0[5])+(s0[6]+s0[7])));
  float acc1 = ub[(n1 & 1023) * 64 + lane]
             + (((s1[0]+s1[1])+(s1[2]+s1[3]))+((s1[4]+s1[5])+(s1[6]+s1[7])));
  float r0 = fmaxf(acc0 + ba1, 0.0f);
  float r1 = fmaxf(acc1 + ba1, 0.0f);
  // h2 = relu(.)@W2a + b2a : one ds_read feeds both nodes, 4 chains each
  float a0=0,a1=0,a2=0,a3=0, c0=0,c1=0,c2=0,c3=0;
  #pragma unroll
  for (int k = 0; k < 64; k += 4) {
    float w0 = sW2[(k    ) * 64 + lane];
    float w1 = sW2[(k + 1) * 64 + lane];
    float w2 = sW2[(k + 2) * 64 + lane];
    float w3 = sW2[(k + 3) * 64 + lane];
    a0 = fmaf(rl(r0, k    ), w0, a0);  c0 = fmaf(rl(r1, k    ), w0, c0);
    a1 = fmaf(rl(r0, k + 1), w1, a1);  c1 = fmaf(rl(r1, k + 1), w1, c1);
    a2 = fmaf(rl(r0, k + 2), w2, a2);  c2 = fmaf(rl(r1, k + 2), w2, c2);
    a3 = fmaf(rl(r0, k + 3), w3, a3);  c3 = fmaf(rl(r1, k + 3), w3, c3);
  }
  float h20 = (ba2 + ((a0 + a1) + (a2 + a3))) * mask[n0];
  float h21 = (ba2 + ((c0 + c1) + (c2 + c3))) * mask[n1];
  // v = h2 @ W1b : halves split k-range, shared weight reads, cross-half add
  float p00=0,p01=0, p10=0,p11=0;
  #pragma unroll
  for (int k0 = 0; k0 < 32; k0 += 2) {
    float w0 = sW1b[(hh * 32 + k0    ) * 32 + f];
    float w1 = sW1b[(hh * 32 + k0 + 1) * 32 + f];
    p00 = fmaf(__shfl(h20, hh * 32 + k0    ), w0, p00);
    p01 = fmaf(__shfl(h20, hh * 32 + k0 + 1), w1, p01);
    p10 = fmaf(__shfl(h21, hh * 32 + k0    ), w0, p10);
    p11 = fmaf(__shfl(h21, hh * 32 + k0 + 1), w1, p11);
  }
  float vp0 = p00 + p01;  vp0 += __shfl_xor(vp0, 32);
  float vp1 = p10 + p11;  vp1 += __shfl_xor(vp1, 32);
  if (hh == 0) {
    v[n0 * 32 + f] = vp0;
    v[n1 * 32 + f] = vp1;
  }
}

// ---------------- layer B: gather v via CSR + MLP -> h3 ----------------
__global__ __launch_bounds__(256) void k_gathB(
    const float* __restrict__ v, const int* __restrict__ nbr,
    const int* __restrict__ deg, const float* __restrict__ mask,
    const float* __restrict__ b1b, const float* __restrict__ W2b,
    const float* __restrict__ b2b, float* __restrict__ h3) {
  __shared__ float sW2b[32 * 32];   // 4 KB
  for (int t = threadIdx.x; t < 32 * 32; t += 256) sW2b[t] = W2b[t];
  __syncthreads();
  int lane = threadIdx.x & 63;
  int f = lane & 31, hh = lane >> 5;
  float bb1 = b1b[f], bb2 = b2b[f];
  int gw = blockIdx.x * 4 + (threadIdx.x >> 6);    // grid 4096 -> 16384 waves
  int n0 = gw * 2, n1 = n0 + 1;
  const float* vb = v + (size_t)(n0 & ~1023) * 32;
  int d0 = deg[n0], d1 = deg[n1];
  int nl0 = nbr[n0 * CAP + lane], nl1 = nbr[n1 * CAP + lane];
  float s0[8] = {0,0,0,0,0,0,0,0}, s1[8] = {0,0,0,0,0,0,0,0};
  int dmax = d0 > d1 ? d0 : d1;
  int rounds = (dmax + 15) >> 4;                   // 16 nbrs/round per node
  for (int rr = 0; rr < rounds; ++rr) {
    int base = rr << 4;
    #pragma unroll
    for (int i = 0; i < 8; ++i) {
      int t = base + (i << 1) + hh;                // halves alternate nbrs
      int j0 = __shfl(nl0, t);
      int j1 = __shfl(nl1, t);
      bool ok0 = t < d0, ok1 = t < d1;
      j0 = ok0 ? j0 : 0;  j1 = ok1 ? j1 : 0;
      float v0 = vb[j0 * 32 + f];
      float v1 = vb[j1 * 32 + f];
      s0[i] += ok0 ? v0 : 0.0f;
      s1[i] += ok1 ? v1 : 0.0f;
    }
  }
  float acc0 = ((s0[0]+s0[1])+(s0[2]+s0[3]))+((s0[4]+s0[5])+(s0[6]+s0[7]));
  float acc1 = ((s1[0]+s1[1])+(s1[2]+s1[3]))+((s1[4]+s1[5])+(s1[6]+s1[7]));
  acc0 += __shfl_xor(acc0, 32);
  acc1 += __shfl_xor(acc1, 32);
  float r0 = fmaxf(vb[(n0 & 1023) * 32 + f] + acc0 + bb1, 0.0f);
  float r1 = fmaxf(vb[(n1 & 1023) * 32 + f] + acc1 + bb1, 0.0f);
  float a0=0,a1=0,a2=0,a3=0, c0=0,c1=0,c2=0,c3=0;
  #pragma unroll
  for (int k = 0; k < 32; k += 4) {
    float w0 = sW2b[(k    ) * 32 + f];
    float w1 = sW2b[(k + 1) * 32 + f];
    float w2 = sW2b[(k + 2) * 32 + f];
    float w3 = sW2b[(k + 3) * 32 + f];
    a0 = fmaf(rl(r0, k    ), w0, a0);  c0 = fmaf(rl(r1, k    ), w0, c0);
    a1 = fmaf(rl(r0, k + 1), w1, a1);  c1 = fmaf(rl(r1, k + 1), w1, c1);
    a2 = fmaf(rl(r0, k + 2), w2, a2);  c2 = fmaf(rl(r1, k + 2), w2, c2);
    a3 = fmaf(rl(r0, k + 3), w3, a3);  c3 = fmaf(rl(r1, k + 3), w3, c3);
  }
  float o0 = (bb2 + ((a0 + a1) + (a2 + a3))) * mask[n0];
  float o1 = (bb2 + ((c0 + c1) + (c2 + c3))) * mask[n1];
  if (hh == 0) {
    h3[n0 * 32 + f] = o0;
    h3[n1 * 32 + f] = o1;
  }
}

// ---------------- readout: g = max_n h3 ; out = g@Wfc + bfc ----------------
__global__ __launch_bounds__(1024) void k_readout(
    const float* __restrict__ h3, const float* __restrict__ Wfc,
    const float* __restrict__ bfc, float* __restrict__ out) {
  __shared__ float red[32][33];
  __shared__ float g[32];
  int b = blockIdx.x;
  int f = threadIdx.x & 31, c = threadIdx.x >> 5;
  const float* hb = h3 + (size_t)b * 1024 * 32;
  float m = -3.4e38f;
  for (int r0 = 0; r0 < 32; ++r0)
    m = fmaxf(m, hb[(c * 32 + r0) * 32 + f]);
  red[c][f] = m;
  __syncthreads();
  if (c == 0) {
    float mm = red[0][f];
    #pragma unroll
    for (int k = 1; k < 32; ++k) mm = fmaxf(mm, red[k][f]);
    g[f] = mm;
  }
  __syncthreads();
  if (threadIdx.x < 10) {
    float o = bfc[threadIdx.x];
    #pragma unroll
    for (int k = 0; k < 32; ++k)
      o = fmaf(g[k], Wfc[k * 10 + threadIdx.x], o);
    out[b * 10 + threadIdx.x] = o;
  }
}

extern "C" void kernel_launch(void* const* d_in, const int* in_sizes, int n_in,
                              void* d_out, int out_size, void* d_ws, size_t ws_size,
                              hipStream_t stream) {
  const float* x    = (const float*)d_in[0];
  const float* adj  = (const float*)d_in[1];
  const float* mask = (const float*)d_in[2];
  const float* W1a  = (const float*)d_in[3];
  const float* b1a  = (const float*)d_in[4];
  const float* W2a  = (const float*)d_in[5];
  const float* b2a  = (const float*)d_in[6];
  const float* W1b  = (const float*)d_in[7];
  const float* b1b  = (const float*)d_in[8];
  const float* W2b  = (const float*)d_in[9];
  const float* b2b  = (const float*)d_in[10];
  const float* Wfc  = (const float*)d_in[11];
  const float* bfc  = (const float*)d_in[12];
  float* out = (float*)d_out;

  // ws layout: u[0,8M) v[8M,12M) nbr[12M,20M) deg[20M,+128K) h3 aliases u
  char* ws = (char*)d_ws;
  float* u   = (float*)(ws);
  float* v   = (float*)(ws + (8u << 20));
  int*   nbr = (int*)  (ws + (12u << 20));
  int*   deg = (int*)  (ws + (20u << 20));
  float* h3  = (float*)(ws);

  hipLaunchKernelGGL(k_scanproj, dim3(9216), dim3(256),  0, stream,
                     x, W1a, u, adj, nbr, deg);
  hipLaunchKernelGGL(k_gathA,    dim3(4096), dim3(256),  0, stream,
                     u, nbr, deg, mask, b1a, W2a, b2a, W1b, v);
  hipLaunchKernelGGL(k_gathB,    dim3(4096), dim3(256),  0, stream,
                     v, nbr, deg, mask, b1b, W2b, b2b, h3);
  hipLaunchKernelGGL(k_readout,  dim3(32),   dim3(1024), 0, stream,
                     h3, Wfc, bfc, out);
}

// Round 4
// 273.952 us; speedup vs baseline: 1.3203x; 1.0870x over previous
//
#include <hip/hip_runtime.h>
#include <cstdint>
#include <cstddef>

// GIN: B=32, N=1024, FIN=128, H1=64, H2=32, OUT=10. adj binary, ~1% dense.
// Round-4:
//  - k_scanproj: NO LDS (W1a read via L1; 32 KB = L1 size) so the 8192 scan
//    blocks run at full occupancy instead of 5 blocks/CU.
//  - XCD-aware block->batch swizzle in both gather kernels: batches b with
//    b%8==x run on XCD x (assuming round-robin blockIdx%8 dispatch), so the
//    gather working set (u: 1 MB/XCD, v: 512 KB/XCD) is L2-resident.
//  - gathB fuses the readout partial-max (pmax[node-block][32]) -> h3 never
//    materialized (saves 8 MB traffic + a pass).
//  - k_fin: reduce 128 partials/batch + FC.

#define CAP 64

typedef float v4f __attribute__((ext_vector_type(4)));

__device__ __forceinline__ float rl(float x, int l) {   // wave-uniform lane bcast
  return __int_as_float(__builtin_amdgcn_readlane(__float_as_int(x), l));
}

// ---------------- fused: proj (u = x@W1a) + scan (adj -> CSR) ----------------
// NO __shared__ anywhere in this kernel: scan occupancy must not pay for it.
__global__ __launch_bounds__(256) void k_scanproj(
    const float* __restrict__ x, const float* __restrict__ W1a,
    float* __restrict__ u,
    const float* __restrict__ adj, int* __restrict__ nbr,
    int* __restrict__ deg) {
  int lane = threadIdx.x & 63;
  int wid  = threadIdx.x >> 6;
  if (blockIdx.x < 1024) {
    // ---- proj: u = x @ W1a, 8 rows/wave; W1a via L1 (exactly 32 KB) ----
    int row0 = (blockIdx.x * 4 + wid) * 8;
    row0 = __builtin_amdgcn_readfirstlane(row0);
    const float* xr = x + (size_t)row0 * 128;
    float acc[8] = {0, 0, 0, 0, 0, 0, 0, 0};
    for (int kc = 0; kc < 32; ++kc) {
      v4f xv[8];
      #pragma unroll
      for (int r = 0; r < 8; ++r)
        xv[r] = *(const v4f*)(xr + r * 128 + kc * 4);
      #pragma unroll
      for (int j = 0; j < 4; ++j) {
        float w = W1a[(kc * 4 + j) * 64 + lane];   // L1-hit after warmup
        #pragma unroll
        for (int r = 0; r < 8; ++r)
          acc[r] = fmaf(xv[r][j], w, acc[r]);
      }
    }
    #pragma unroll
    for (int r = 0; r < 8; ++r)
      u[(size_t)(row0 + r) * 64 + lane] = acc[r];
  } else {
    // ---- scan: one wave per 4 KB adj row, lane-parallel index extraction ----
    int node = (blockIdx.x - 1024) * 4 + wid;      // 8192 blocks -> 32768 rows
    const v4f* arow = (const v4f*)(adj + (size_t)node * 1024);
    int* outp = nbr + node * CAP;
    v4f a[4];
    #pragma unroll
    for (int c = 0; c < 4; ++c)
      a[c] = __builtin_nontemporal_load(arow + c * 64 + lane);
    int cnt = 0;
    #pragma unroll
    for (int c = 0; c < 4; ++c) {
      #pragma unroll
      for (int comp = 0; comp < 4; ++comp) {
        bool hit = (a[c][comp] != 0.0f);
        unsigned long long m = __ballot(hit);
        if (hit) {
          int below = __builtin_amdgcn_mbcnt_hi(
              (unsigned)(m >> 32),
              __builtin_amdgcn_mbcnt_lo((unsigned)m, 0));
          int pos = cnt + below;
          if (pos < CAP) outp[pos] = ((c * 64 + lane) << 2) + comp;
        }
        cnt += __popcll(m);
      }
    }
    if (lane == 0) deg[node] = cnt < CAP ? cnt : CAP;
  }
}

// ---------------- layer A: gather u via CSR + MLP -> v ----------------
// XCD swizzle: block i -> xcd=i&7, j=i>>3; batch b = xcd + 8*(j&3);
// within-batch chunk w = j>>2 (0..127). Each XCD sees 4 batches -> u
// footprint 1 MB (L2-resident). 2 nodes/wave, 16 gathers in flight.
__global__ __launch_bounds__(256) void k_gathA(
    const float* __restrict__ u, const int* __restrict__ nbr,
    const int* __restrict__ deg, const float* __restrict__ mask,
    const float* __restrict__ b1a, const float* __restrict__ W2a,
    const float* __restrict__ b2a, const float* __restrict__ W1b,
    float* __restrict__ v) {
  __shared__ float sW2[64 * 64];    // 16 KB
  __shared__ float sW1b[64 * 32];   // 8 KB
  for (int t = threadIdx.x; t < 64 * 64; t += 256) sW2[t] = W2a[t];
  for (int t = threadIdx.x; t < 64 * 32; t += 256) sW1b[t] = W1b[t];
  __syncthreads();
  int lane = threadIdx.x & 63;
  int f = lane & 31, hh = lane >> 5;
  float ba1 = b1a[lane], ba2 = b2a[lane];
  int i = blockIdx.x, wid = threadIdx.x >> 6;
  int xcd = i & 7, j = i >> 3;
  int b = xcd + 8 * (j & 3);
  int w = j >> 2;                                  // 0..127
  int n0 = b * 1024 + w * 8 + wid * 2, n1 = n0 + 1;
  const float* ub = u + (size_t)b * 1024 * 64;
  int d0 = deg[n0], d1 = deg[n1];
  int nl0 = nbr[n0 * CAP + lane], nl1 = nbr[n1 * CAP + lane];
  float s0[8] = {0,0,0,0,0,0,0,0}, s1[8] = {0,0,0,0,0,0,0,0};
  int dmax = d0 > d1 ? d0 : d1;
  int rounds = (dmax + 7) >> 3;
  for (int rr = 0; rr < rounds; ++rr) {
    int base = rr << 3;
    #pragma unroll
    for (int i2 = 0; i2 < 8; ++i2) {
      int t = base + i2;
      int j0 = __builtin_amdgcn_readlane(nl0, t);
      int j1 = __builtin_amdgcn_readlane(nl1, t);
      bool ok0 = t < d0, ok1 = t < d1;
      j0 = ok0 ? j0 : 0;  j1 = ok1 ? j1 : 0;
      float v0 = ub[j0 * 64 + lane];               // L2-local 256 B gathers
      float v1 = ub[j1 * 64 + lane];
      s0[i2] += ok0 ? v0 : 0.0f;
      s1[i2] += ok1 ? v1 : 0.0f;
    }
  }
  float acc0 = ub[(n0 & 1023) * 64 + lane]
             + (((s0[0]+s0[1])+(s0[2]+s0[3]))+((s0[4]+s0[5])+(s0[6]+s0[7])));
  float acc1 = ub[(n1 & 1023) * 64 + lane]
             + (((s1[0]+s1[1])+(s1[2]+s1[3]))+((s1[4]+s1[5])+(s1[6]+s1[7])));
  float r0 = fmaxf(acc0 + ba1, 0.0f);
  float r1 = fmaxf(acc1 + ba1, 0.0f);
  float a0=0,a1=0,a2=0,a3=0, c0=0,c1=0,c2=0,c3=0;
  #pragma unroll
  for (int k = 0; k < 64; k += 4) {
    float w0 = sW2[(k    ) * 64 + lane];
    float w1 = sW2[(k + 1) * 64 + lane];
    float w2 = sW2[(k + 2) * 64 + lane];
    float w3 = sW2[(k + 3) * 64 + lane];
    a0 = fmaf(rl(r0, k    ), w0, a0);  c0 = fmaf(rl(r1, k    ), w0, c0);
    a1 = fmaf(rl(r0, k + 1), w1, a1);  c1 = fmaf(rl(r1, k + 1), w1, c1);
    a2 = fmaf(rl(r0, k + 2), w2, a2);  c2 = fmaf(rl(r1, k + 2), w2, c2);
    a3 = fmaf(rl(r0, k + 3), w3, a3);  c3 = fmaf(rl(r1, k + 3), w3, c3);
  }
  float h20 = (ba2 + ((a0 + a1) + (a2 + a3))) * mask[n0];
  float h21 = (ba2 + ((c0 + c1) + (c2 + c3))) * mask[n1];
  float p00=0,p01=0, p10=0,p11=0;
  #pragma unroll
  for (int k0 = 0; k0 < 32; k0 += 2) {
    float w0 = sW1b[(hh * 32 + k0    ) * 32 + f];
    float w1 = sW1b[(hh * 32 + k0 + 1) * 32 + f];
    p00 = fmaf(__shfl(h20, hh * 32 + k0    ), w0, p00);
    p01 = fmaf(__shfl(h20, hh * 32 + k0 + 1), w1, p01);
    p10 = fmaf(__shfl(h21, hh * 32 + k0    ), w0, p10);
    p11 = fmaf(__shfl(h21, hh * 32 + k0 + 1), w1, p11);
  }
  float vp0 = p00 + p01;  vp0 += __shfl_xor(vp0, 32);
  float vp1 = p10 + p11;  vp1 += __shfl_xor(vp1, 32);
  if (hh == 0) {
    v[n0 * 32 + f] = vp0;
    v[n1 * 32 + f] = vp1;
  }
}

// ---------------- layer B: gather v via CSR + MLP + block-max -> pmax --------
// Same XCD swizzle (v: 512 KB/XCD in L2; nbr re-hit from gathA). h3 never
// written: each block (8 nodes) emits its feature-max into pmax[b*128+w][32].
__global__ __launch_bounds__(256) void k_gathB(
    const float* __restrict__ v, const int* __restrict__ nbr,
    const int* __restrict__ deg, const float* __restrict__ mask,
    const float* __restrict__ b1b, const float* __restrict__ W2b,
    const float* __restrict__ b2b, float* __restrict__ pmax) {
  __shared__ float sW2b[32 * 32];   // 4 KB
  __shared__ float wred[4][32];
  for (int t = threadIdx.x; t < 32 * 32; t += 256) sW2b[t] = W2b[t];
  __syncthreads();
  int lane = threadIdx.x & 63;
  int f = lane & 31, hh = lane >> 5;
  float bb1 = b1b[f], bb2 = b2b[f];
  int i = blockIdx.x, wid = threadIdx.x >> 6;
  int xcd = i & 7, j = i >> 3;
  int b = xcd + 8 * (j & 3);
  int w = j >> 2;                                  // 0..127
  int n0 = b * 1024 + w * 8 + wid * 2, n1 = n0 + 1;
  const float* vb = v + (size_t)b * 1024 * 32;
  int d0 = deg[n0], d1 = deg[n1];
  int nl0 = nbr[n0 * CAP + lane], nl1 = nbr[n1 * CAP + lane];
  float s0[8] = {0,0,0,0,0,0,0,0}, s1[8] = {0,0,0,0,0,0,0,0};
  int dmax = d0 > d1 ? d0 : d1;
  int rounds = (dmax + 15) >> 4;
  for (int rr = 0; rr < rounds; ++rr) {
    int base = rr << 4;
    #pragma unroll
    for (int i2 = 0; i2 < 8; ++i2) {
      int t = base + (i2 << 1) + hh;               // halves alternate nbrs
      int j0 = __shfl(nl0, t);
      int j1 = __shfl(nl1, t);
      bool ok0 = t < d0, ok1 = t < d1;
      j0 = ok0 ? j0 : 0;  j1 = ok1 ? j1 : 0;
      float v0 = vb[j0 * 32 + f];
      float v1 = vb[j1 * 32 + f];
      s0[i2] += ok0 ? v0 : 0.0f;
      s1[i2] += ok1 ? v1 : 0.0f;
    }
  }
  float acc0 = ((s0[0]+s0[1])+(s0[2]+s0[3]))+((s0[4]+s0[5])+(s0[6]+s0[7]));
  float acc1 = ((s1[0]+s1[1])+(s1[2]+s1[3]))+((s1[4]+s1[5])+(s1[6]+s1[7]));
  acc0 += __shfl_xor(acc0, 32);
  acc1 += __shfl_xor(acc1, 32);
  float r0 = fmaxf(vb[(n0 & 1023) * 32 + f] + acc0 + bb1, 0.0f);
  float r1 = fmaxf(vb[(n1 & 1023) * 32 + f] + acc1 + bb1, 0.0f);
  float a0=0,a1=0,a2=0,a3=0, c0=0,c1=0,c2=0,c3=0;
  #pragma unroll
  for (int k = 0; k < 32; k += 4) {
    float w0 = sW2b[(k    ) * 32 + f];
    float w1 = sW2b[(k + 1) * 32 + f];
    float w2 = sW2b[(k + 2) * 32 + f];
    float w3 = sW2b[(k + 3) * 32 + f];
    a0 = fmaf(rl(r0, k    ), w0, a0);  c0 = fmaf(rl(r1, k    ), w0, c0);
    a1 = fmaf(rl(r0, k + 1), w1, a1);  c1 = fmaf(rl(r1, k + 1), w1, c1);
    a2 = fmaf(rl(r0, k + 2), w2, a2);  c2 = fmaf(rl(r1, k + 2), w2, c2);
    a3 = fmaf(rl(r0, k + 3), w3, a3);  c3 = fmaf(rl(r1, k + 3), w3, c3);
  }
  float o0 = (bb2 + ((a0 + a1) + (a2 + a3))) * mask[n0];
  float o1 = (bb2 + ((c0 + c1) + (c2 + c3))) * mask[n1];
  // per-wave max of the 2 nodes (o identical on both halves), then block max
  float m = fmaxf(o0, o1);
  if (hh == 0) wred[wid][f] = m;
  __syncthreads();
  if (threadIdx.x < 32) {
    float mm = fmaxf(fmaxf(wred[0][threadIdx.x], wred[1][threadIdx.x]),
                     fmaxf(wred[2][threadIdx.x], wred[3][threadIdx.x]));
    pmax[((b << 7) + w) * 32 + threadIdx.x] = mm;
  }
}

// ---------------- final: g = max_w pmax ; out = g@Wfc + bfc ----------------
__global__ __launch_bounds__(1024) void k_fin(
    const float* __restrict__ pmax, const float* __restrict__ Wfc,
    const float* __restrict__ bfc, float* __restrict__ out) {
  __shared__ float red[32][33];
  __shared__ float g[32];
  int b = blockIdx.x;
  int f = threadIdx.x & 31, c = threadIdx.x >> 5;  // 32 chunks of 4 partials
  const float* pb = pmax + (size_t)b * 128 * 32;
  float m = -3.4e38f;
  #pragma unroll
  for (int q = 0; q < 4; ++q)
    m = fmaxf(m, pb[(c * 4 + q) * 32 + f]);
  red[c][f] = m;
  __syncthreads();
  if (c == 0) {
    float mm = red[0][f];
    #pragma unroll
    for (int k = 1; k < 32; ++k) mm = fmaxf(mm, red[k][f]);
    g[f] = mm;
  }
  __syncthreads();
  if (threadIdx.x < 10) {
    float o = bfc[threadIdx.x];
    #pragma unroll
    for (int k = 0; k < 32; ++k)
      o = fmaf(g[k], Wfc[k * 10 + threadIdx.x], o);
    out[b * 10 + threadIdx.x] = o;
  }
}

extern "C" void kernel_launch(void* const* d_in, const int* in_sizes, int n_in,
                              void* d_out, int out_size, void* d_ws, size_t ws_size,
                              hipStream_t stream) {
  const float* x    = (const float*)d_in[0];
  const float* adj  = (const float*)d_in[1];
  const float* mask = (const float*)d_in[2];
  const float* W1a  = (const float*)d_in[3];
  const float* b1a  = (const float*)d_in[4];
  const float* W2a  = (const float*)d_in[5];
  const float* b2a  = (const float*)d_in[6];
  const float* W1b  = (const float*)d_in[7];
  const float* b1b  = (const float*)d_in[8];
  const float* W2b  = (const float*)d_in[9];
  const float* b2b  = (const float*)d_in[10];
  const float* Wfc  = (const float*)d_in[11];
  const float* bfc  = (const float*)d_in[12];
  float* out = (float*)d_out;

  // ws: u[0,8M) v[8M,12M) nbr[12M,20M) deg[20M,+128K) pmax[21M,+512K)
  char* ws = (char*)d_ws;
  float* u    = (float*)(ws);
  float* v    = (float*)(ws + (8u << 20));
  int*   nbr  = (int*)  (ws + (12u << 20));
  int*   deg  = (int*)  (ws + (20u << 20));
  float* pmax = (float*)(ws + (21u << 20));

  hipLaunchKernelGGL(k_scanproj, dim3(9216), dim3(256),  0, stream,
                     x, W1a, u, adj, nbr, deg);
  hipLaunchKernelGGL(k_gathA,    dim3(4096), dim3(256),  0, stream,
                     u, nbr, deg, mask, b1a, W2a, b2a, W1b, v);
  hipLaunchKernelGGL(k_gathB,    dim3(4096), dim3(256),  0, stream,
                     v, nbr, deg, mask, b1b, W2b, b2b, pmax);
  hipLaunchKernelGGL(k_fin,      dim3(32),   dim3(1024), 0, stream,
                     pmax, Wfc, bfc, out);
}